// Round 5
// baseline (330.349 us; speedup 1.0000x reference)
//
#include <hip/hip_runtime.h>

typedef unsigned short u16;
typedef __attribute__((ext_vector_type(8))) short bf16x8;
typedef __attribute__((ext_vector_type(4))) float f32x4;
typedef __attribute__((ext_vector_type(4))) u16 u16x4;

#define MFMA16(a, b, c) __builtin_amdgcn_mfma_f32_16x16x32_bf16(a, b, c, 0, 0, 0)

__device__ __forceinline__ u16 f2bf(float f) {
    union { float f; unsigned u; } v; v.f = f;
    unsigned r = (v.u + 0x7FFFu + ((v.u >> 16) & 1u)) >> 16;  // RNE
    return (u16)r;
}

__device__ __forceinline__ void gload_lds16(const void* g, void* l) {
    __builtin_amdgcn_global_load_lds((const __attribute__((address_space(1))) void*)g,
                                     (__attribute__((address_space(3))) void*)l, 16, 0, 0);
}

// ---------- prep: fp32 -> bf16 (optionally scaled) ----------
__global__ __launch_bounds__(256) void cvt_kernel(const float* __restrict__ src,
                                                  u16* __restrict__ dst, int n4, float scale) {
    int i = blockIdx.x * 256 + threadIdx.x;
    if (i >= n4) return;
    f32x4 v = *(const f32x4*)(src + (size_t)i * 4);
    u16x4 o;
#pragma unroll
    for (int j = 0; j < 4; ++j) o[j] = f2bf(v[j] * scale);
    *(u16x4*)(dst + (size_t)i * 4) = o;
}

// ---------- prep: V (8192x512 f32) -> Vt (512x8192 bf16) ----------
__global__ __launch_bounds__(256) void prep_vt(const float* __restrict__ V, u16* __restrict__ Vt) {
    __shared__ float tile[64][65];
    int t = threadIdx.x;
    int n0 = blockIdx.x * 64;
    int d0 = blockIdx.y * 64;
    int tr = t >> 4, tc = t & 15;
#pragma unroll
    for (int p = 0; p < 4; ++p) {
        int n = p * 16 + tr;
        f32x4 v = *(const f32x4*)(V + (size_t)(n0 + n) * 512 + d0 + tc * 4);
#pragma unroll
        for (int j = 0; j < 4; ++j) tile[n][tc * 4 + j] = v[j];
    }
    __syncthreads();
#pragma unroll
    for (int p = 0; p < 4; ++p) {
        int d = p * 16 + tr;
        u16x4 o;
#pragma unroll
        for (int j = 0; j < 4; ++j) o[j] = f2bf(tile[tc * 4 + j][d]);
        *(u16x4*)(Vt + (size_t)(d0 + d) * 8192 + n0 + tc * 4) = o;
    }
}

// ---------- flash attention: BM=32, KVBLK=32, key-split 2, 2 blocks/CU ----------
// 8 waves = wr(2 row-strips x16) x wc(2 key-strips x16) x kh(2 k-halves x256).
// Each wave computes a 16x16 S-partial over its k-half; pairs (wid, wid^1)
// exchange partials through lds_sx; kh==0 waves do exp + P-write.
__global__ __launch_bounds__(512, 4) void flash_kernel(
    const u16* __restrict__ Qs, const u16* __restrict__ Kb, const u16* __restrict__ Vt,
    float* __restrict__ Opart, float* __restrict__ lpart) {
    __shared__ __align__(16) u16 lds_k[2][32 * 512];   // double-buffered K tile (64 KB), XOR swizzle
    __shared__ __align__(16) float lds_sx[8 * 256];    // S-partial exchange (8 KB)
    __shared__ __align__(16) u16 lds_p[32 * 32];       // P tile (2 KB, linear)
    __shared__ float s_l[2][32];

    const int tid = threadIdx.x;
    const int wid = tid >> 6;
    const int lane = tid & 63;
    const int lo = lane & 15;
    const int hi = lane >> 4;
    const int wr = wid >> 2;        // row strip (2 x 16 rows)
    const int wc = (wid >> 1) & 1;  // key strip (2 x 16 keys)
    const int kh = wid & 1;         // k-half (2 x 256)

    // block mapping: same-XCD blocks share a key-split; pair (bx, bx+256) -> same CU, same stream
    const int bx = blockIdx.x;
    const int x = bx & 7;
    const int ks = x >> 2;
    const int mtile = (bx >> 3) * 4 + (x & 3);  // 0..255
    const int key0 = ks * 4096;

    // Q fragments (B-operand of swapped S-MFMA): wave's 16 rows, its k-half. 32 VGPR.
    bf16x8 qf[8];
    {
        const u16* qrow = Qs + (size_t)(mtile * 32 + wr * 16 + lo) * 512 + kh * 256 + hi * 8;
#pragma unroll
        for (int j = 0; j < 8; ++j) qf[j] = *(const bf16x8*)(qrow + j * 32);
    }

    f32x4 o[2][4];
#pragma unroll
    for (int a = 0; a < 2; ++a)
#pragma unroll
        for (int b = 0; b < 4; ++b) o[a][b] = (f32x4){0.f, 0.f, 0.f, 0.f};
    float lsum = 0.f;

    // S-phase LDS addressing: global chunk c = kt*4+hi at LDS chunk c^(row&7), row = wc*16+lo.
    const int srow = wc * 16 + lo;
    const int base_e = srow * 512 + kh * 256 + ((hi ^ (lo & 7)) << 3);  // j even
    const int base_o = base_e ^ 32;                                     // j odd (flips bit2 of chunk)
    const int sxw = wid * 256 + lo * 16 + hi * 4;
    const int sxr = (wid ^ 1) * 256 + lo * 16 + hi * 4;
    const int pw = (wr * 16 + lo) * 32 + wc * 16 + hi * 4;

    // prologue: stage K tile 0 into buf 0 (8 waves x 4 rows)
    {
        const u16* kbase = Kb + (size_t)key0 * 512;
#pragma unroll
        for (int r4 = 0; r4 < 4; ++r4) {
            int row = wid * 4 + r4;
            gload_lds16(kbase + (size_t)row * 512 + ((lane ^ (row & 7)) << 3),
                        &lds_k[0][row * 512]);
        }
    }

    for (int it = 0; it < 128; ++it) {
        const int cur = it & 1;
        // ---- top barrier: stage(it) landed (vmcnt only) ----
        asm volatile("s_waitcnt vmcnt(0)\n\ts_barrier" ::: "memory");

        // ---- V B-fragments FIRST (so PV's vb-wait is vmcnt(4), not chained behind stage) ----
        bf16x8 vb[4];
#pragma unroll
        for (int nt = 0; nt < 4; ++nt)
            vb[nt] = *(const bf16x8*)(Vt + (size_t)(wid * 64 + nt * 16 + lo) * 8192 +
                                      key0 + it * 32 + hi * 8);
        asm volatile("" ::: "memory");  // pin vb issue before stage issue

        // ---- stage K[it+1] into buf[cur^1]: in flight across the whole iter ----
        if (it + 1 < 128) {
            const u16* kbase = Kb + (size_t)(key0 + (it + 1) * 32) * 512;
#pragma unroll
            for (int r4 = 0; r4 < 4; ++r4) {
                int row = wid * 4 + r4;
                gload_lds16(kbase + (size_t)row * 512 + ((lane ^ (row & 7)) << 3),
                            &lds_k[cur ^ 1][row * 512]);
            }
        }

        // ---- S-partial = K(16 keys) x Q(16 rows) over k-half: 8 chained MFMAs ----
        f32x4 s = {0.f, 0.f, 0.f, 0.f};
        {
            const u16* kb = &lds_k[cur][0];
            __builtin_amdgcn_s_setprio(1);
#pragma unroll
            for (int j2 = 0; j2 < 4; ++j2) {
                bf16x8 ae = *(const bf16x8*)(kb + base_e + j2 * 64);
                bf16x8 ao = *(const bf16x8*)(kb + base_o + j2 * 64);
                s = MFMA16(ae, qf[2 * j2], s);
                s = MFMA16(ao, qf[2 * j2 + 1], s);
            }
            __builtin_amdgcn_s_setprio(0);
        }
        *(f32x4*)(&lds_sx[sxw]) = s;

        // ---- bar2: S-partials visible ----
        asm volatile("s_waitcnt lgkmcnt(0)\n\ts_barrier" ::: "memory");

        // ---- kh==0 waves: combine partials, exp, write P ----
        if (kh == 0) {
            f32x4 sp = *(const f32x4*)(&lds_sx[sxr]);
            u16x4 w;
#pragma unroll
            for (int r = 0; r < 4; ++r) {
                float p = __expf(s[r] + sp[r]);
                lsum += p;
                w[r] = f2bf(p);
            }
            *(u16x4*)(&lds_p[pw]) = w;
        }

        // ---- bar3: P visible ----
        asm volatile("s_waitcnt lgkmcnt(0)\n\ts_barrier" ::: "memory");

        // ---- PV: wave owns O cols [wid*64,+64); P from lds_p, V from regs ----
        __builtin_amdgcn_s_setprio(1);
#pragma unroll
        for (int mt = 0; mt < 2; ++mt) {
            bf16x8 pa = *(const bf16x8*)(&lds_p[(mt * 16 + lo) * 32 + hi * 8]);
#pragma unroll
            for (int nt = 0; nt < 4; ++nt) o[mt][nt] = MFMA16(pa, vb[nt], o[mt][nt]);
        }
        __builtin_amdgcn_s_setprio(0);
    }

    // ---- epilogue ----
    lsum += __shfl_xor(lsum, 16);
    lsum += __shfl_xor(lsum, 32);
    const int lb = mtile * 2 + ks;
    if (kh == 0 && lane < 16) s_l[wc][wr * 16 + lo] = lsum;
    __syncthreads();

    {
        float* Ob = Opart + (size_t)lb * (32 * 512);
#pragma unroll
        for (int mt = 0; mt < 2; ++mt)
#pragma unroll
            for (int nt = 0; nt < 4; ++nt)
#pragma unroll
                for (int r = 0; r < 4; ++r) {
                    int row = mt * 16 + hi * 4 + r;
                    int col = wid * 64 + nt * 16 + lo;
                    Ob[row * 512 + col] = o[mt][nt][r];
                }
        if (tid < 32) lpart[lb * 32 + tid] = s_l[0][tid] + s_l[1][tid];
    }
}

// ---------- combine the 2 key-split partials: out = (O0+O1)/(l0+l1) ----------
__global__ __launch_bounds__(256) void combine_kernel(const float* __restrict__ Opart,
                                                      const float* __restrict__ lpart,
                                                      float* __restrict__ out) {
    int i = blockIdx.x * 256 + threadIdx.x;  // float4 index; 8192*512/4 = 1048576 total
    int row = i >> 7;
    int c4 = i & 127;
    int mtile = row >> 5, rl = row & 31;
    int b0 = mtile * 2, b1 = b0 + 1;
    float inv = 1.0f / (lpart[b0 * 32 + rl] + lpart[b1 * 32 + rl]);
    f32x4 a = *(const f32x4*)(Opart + (size_t)b0 * 16384 + rl * 512 + c4 * 4);
    f32x4 b = *(const f32x4*)(Opart + (size_t)b1 * 16384 + rl * 512 + c4 * 4);
    f32x4 r = (a + b) * inv;
    *(f32x4*)(out + (size_t)row * 512 + c4 * 4) = r;
}

extern "C" void kernel_launch(void* const* d_in, const int* in_sizes, int n_in,
                              void* d_out, int out_size, void* d_ws, size_t ws_size,
                              hipStream_t stream) {
    const float* Q = (const float*)d_in[0];
    const float* K = (const float*)d_in[1];
    const float* V = (const float*)d_in[2];
    float* out = (float*)d_out;
    char* ws = (char*)d_ws;

    // ws layout (bytes): Qs 8M | Kb 8M | Vt 8M | Opart 32M | lpart 64K
    u16* Qs = (u16*)(ws + 0);
    u16* Kb = (u16*)(ws + 8388608);
    u16* Vt = (u16*)(ws + 16777216);
    float* Op = (float*)(ws + 25165824);
    float* lp = (float*)(ws + 58720256);

    const float scale = 0.08838834764831845f;  // 2 / sqrt(512): softmax(s)^2 renorm == softmax(2s)
    cvt_kernel<<<4096, 256, 0, stream>>>(Q, Qs, 1048576, scale);
    cvt_kernel<<<4096, 256, 0, stream>>>(K, Kb, 1048576, 1.0f);
    prep_vt<<<dim3(128, 8), 256, 0, stream>>>(V, Vt);
    flash_kernel<<<512, 512, 0, stream>>>(Qs, Kb, Vt, Op, lp);
    combine_kernel<<<4096, 256, 0, stream>>>(Op, lp, out);
}